// Round 3
// baseline (82.874 us; speedup 1.0000x reference)
//
#include <hip/hip_runtime.h>
#include <math.h>

// L=13, M=12, ODD_KS=(1,3,5) -> NK=3
#define LL    13
#define MM    12
#define NKK   3
#define TILE  64                  // t's per block
#define SLICES 4                  // waves per block, each takes 6 of 24 d-values
#define BLOCK (TILE * SLICES)
#define HALO  24                  // window spans [t-24, t+24]
#define WIN   (TILE + 2 * HALO)   // 112
#define DTOT  (LL + MM - 1)       // 24
#define DPS   (DTOT / SLICES)     // 6

// LDS index map (window base t0-24), i = t - t0:
//   x1(l)    -> Z[i + l + 12]      B-powers(l,m) -> P[i + l + m]
//   x3l(l)   -> Z[i + l + 36]      C-powers(l,m) -> P[i + l + m + 24]

#define SLICE_BODY(S)                                                   \
  { _Pragma("unroll")                                                   \
    for (int d = DPS * (S); d < DPS * (S) + DPS; ++d) {                 \
      const float4 p = sP[i + d];                                       \
      const float4 q = sP[i + d + HALO];                                \
      _Pragma("unroll")                                                 \
      for (int l = 0; l < LL; ++l) {                                    \
        const int m = d - l;                                            \
        if (m >= 0 && m < MM) {  /* folds at compile time */            \
          const float* bp = Bc + (l * MM + m) * NKK;                    \
          cB[l] += bp[0] * p.x + bp[1] * p.y + bp[2] * p.z;             \
          const float* cp = Cc + (l * MM + m) * NKK;                    \
          cC[l] += cp[0] * q.x + cp[1] * q.y + cp[2] * q.z;             \
        }                                                               \
      }                                                                 \
    } }

__global__ __launch_bounds__(BLOCK)
void gmp_kernel(const float* __restrict__ x,    // (B,T,2)
                const float* __restrict__ Ac,   // (L,NK)
                const float* __restrict__ Bc,   // (L,M,NK)
                const float* __restrict__ Cc,   // (L,M,NK)
                float* __restrict__ out,        // (B,T,2)
                int T, int tilesPerB)
{
    __shared__ float4 sP[WIN];            // {a, a^3, a^5, 0}
    __shared__ float2 sZ[WIN];            // {re, im}
    __shared__ float2 sRed[SLICES][TILE]; // per-slice partial (sr,si)

    const int tid = threadIdx.x;
    const int i   = tid & (TILE - 1);     // t within tile
    const int s   = tid >> 6;             // slice == wave id (uniform per wave)
    const int b   = blockIdx.x / tilesPerB;
    const int t0  = (blockIdx.x % tilesPerB) * TILE;

    const float* xb = x + (size_t)b * T * 2;

    // Stage 112-sample window with circular wrap; powers computed once per sample
    for (int j = tid; j < WIN; j += BLOCK) {
        int t = t0 - HALO + j;
        if (t < 0)  t += T;
        if (t >= T) t -= T;
        float re = xb[2 * t], im = xb[2 * t + 1];
        float a2 = re * re + im * im;
        float a  = sqrtf(a2);
        sZ[j] = make_float2(re, im);
        sP[j] = make_float4(a, a * a2, a * a2 * a2, 0.0f);
    }
    __syncthreads();

    float cB[LL], cC[LL];
    #pragma unroll
    for (int l = 0; l < LL; ++l) { cB[l] = 0.0f; cC[l] = 0.0f; }

    // Wave-uniform compile-time dispatch: keeps coefficient offsets constant
    // (s_load broadcasts) and the m-guard foldable.
    if (s == 0) {
        SLICE_BODY(0)
        // A-term (p1 . A[l]) handled by slice 0 only
        #pragma unroll
        for (int l = 0; l < LL; ++l) {
            const float4 p = sP[i + l + 12];
            cB[l] += Ac[l * NKK + 0] * p.x
                   + Ac[l * NKK + 1] * p.y
                   + Ac[l * NKK + 2] * p.z;
        }
    } else if (s == 1) {
        SLICE_BODY(1)
    } else if (s == 2) {
        SLICE_BODY(2)
    } else {
        SLICE_BODY(3)
    }

    // Per-slice partial epilogue: sum_l x1*cB + x3_last*cC
    float sr = 0.0f, si = 0.0f;
    #pragma unroll
    for (int l = 0; l < LL; ++l) {
        const float2 z1 = sZ[i + l + 12];
        const float2 z3 = sZ[i + l + 36];
        sr += z1.x * cB[l] + z3.x * cC[l];
        si += z1.y * cB[l] + z3.y * cC[l];
    }
    sRed[s][i] = make_float2(sr, si);
    __syncthreads();

    if (s == 0) {
        const float2 r0 = sRed[0][i], r1 = sRed[1][i];
        const float2 r2 = sRed[2][i], r3 = sRed[3][i];
        const int t = t0 + i;
        if (t < T) {
            out[((size_t)b * T + t) * 2 + 0] = r0.x + r1.x + r2.x + r3.x;
            out[((size_t)b * T + t) * 2 + 1] = r0.y + r1.y + r2.y + r3.y;
        }
    }
}

extern "C" void kernel_launch(void* const* d_in, const int* in_sizes, int n_in,
                              void* d_out, int out_size, void* d_ws, size_t ws_size,
                              hipStream_t stream)
{
    // Inputs: x (B,T,2) f32, h_0 (B,16) f32 [unused], A_kl (L,NK),
    // B_klm (L,M,NK), C_klm (L,M,NK)
    const float* x  = (const float*)d_in[0];
    const float* Ac = (const float*)d_in[2];
    const float* Bc = (const float*)d_in[3];
    const float* Cc = (const float*)d_in[4];
    float* out = (float*)d_out;

    const int Bsz = in_sizes[1] / 16;               // h_0 is (B,16)
    const int T   = in_sizes[0] / (2 * Bsz);        // x is (B,T,2)
    const int tilesPerB = (T + TILE - 1) / TILE;    // 128 for T=8192

    dim3 grid(Bsz * tilesPerB);                     // 2048 blocks
    dim3 block(BLOCK);                              // 256 threads = 4 waves
    gmp_kernel<<<grid, block, 0, stream>>>(x, Ac, Bc, Cc, out, T, tilesPerB);
}